// Round 1
// baseline (83.465 us; speedup 1.0000x reference)
//
#include <hip/hip_runtime.h>

#define NB 16      // batch
#define NC 128     // bands
#define NR 64      // resolution
#define NF 128     // frames
#define NS 32768   // samples
#define TS 64      // samples per tile in mix kernel
#define CPAD 132   // padded LDS row stride (floats) — kills 4-way bank conflict

// Kernel A: per (b,c) row — softmax over resolution, then matvec with
// resonance (R x F) -> framesT stored TRANSPOSED as (f, b, c) so the mix
// kernel can stage frame columns with coalesced float4 loads.
__global__ __launch_bounds__(64) void frames_kernel(
    const float* __restrict__ x,         // (B, C, R)
    const float* __restrict__ resonance, // (R, F)
    float* __restrict__ framesT)         // (F, B*C)
{
    const int row = blockIdx.x;   // b*128 + c
    const int r   = threadIdx.x;  // 0..63  (one wave)

    float xv = x[row * NR + r];

    // wave-64 max reduction
    float m = xv;
    #pragma unroll
    for (int off = 32; off >= 1; off >>= 1)
        m = fmaxf(m, __shfl_xor(m, off, 64));
    float e = __expf(xv - m);
    float ssum = e;
    #pragma unroll
    for (int off = 32; off >= 1; off >>= 1)
        ssum += __shfl_xor(ssum, off, 64);
    float p = e / ssum;

    __shared__ float psh[NR];
    psh[r] = p;
    __syncthreads();

    // thread r computes frames for f = r and f = r + 64
    float acc0 = 0.f, acc1 = 0.f;
    #pragma unroll 8
    for (int rr = 0; rr < NR; ++rr) {
        float pr = psh[rr];
        acc0 = fmaf(pr, resonance[rr * NF + r],      acc0);
        acc1 = fmaf(pr, resonance[rr * NF + r + 64], acc1);
    }
    framesT[r        * (NB * NC) + row] = acc0;
    framesT[(r + 64) * (NB * NC) + row] = acc1;
}

// Kernel B: tile of TS=64 samples per block; i0/i1 are uniform per tile
// (floor((s+0.5)/256-0.5) is constant over an aligned 64-run).
//
// Lane mapping change vs previous version: wave = 16 batches x 4 sample
// groups (b = lane>>2, sgl = lane&3) instead of (sg = tid&15, b = tid>>4).
// The 16-way batch replication of the fbank read now sits INSIDE the
// coalescing window -> each wave-load touches one 64 B line instead of 4.
// LDS frame tiles padded to stride CPAD=132 -> bank stride 4 per batch,
// worst-case 2-way (free) instead of 4-way conflict.
__global__ __launch_bounds__(256) void mix_kernel(
    const float* __restrict__ framesT, // (F, B*C)
    const float* __restrict__ fbank,   // (C, S)
    float* __restrict__ out)           // (B, S)
{
    __shared__ float g0[NB * CPAD];
    __shared__ float g1[NB * CPAD];

    const int base = blockIdx.x * TS;
    const int tid  = threadIdx.x;

    // tile-uniform frame indices
    float posb = (base + 0.5f) * (1.0f / 256.0f) - 0.5f;
    int i0 = (int)floorf(posb);
    i0 = i0 < 0 ? 0 : (i0 > NF - 1 ? NF - 1 : i0);
    const int i1 = (i0 + 1 < NF) ? i0 + 1 : NF - 1;

    {   // stage 2 x 8 KB with float4 into padded [b][c] layout
        const float4* src0 = (const float4*)(framesT + (size_t)i0 * (NB * NC));
        const float4* src1 = (const float4*)(framesT + (size_t)i1 * (NB * NC));
        int bb = tid >> 5;              // (tid*4) >> 7
        int cc = (tid & 31) * 4;        // (tid*4) & 127
        *(float4*)&g0[bb * CPAD + cc] = src0[tid];
        *(float4*)&g1[bb * CPAD + cc] = src1[tid];
        bb = (tid + 256) >> 5;
        cc = ((tid + 256) & 31) * 4;
        *(float4*)&g0[bb * CPAD + cc] = src0[tid + 256];
        *(float4*)&g1[bb * CPAD + cc] = src1[tid + 256];
    }
    __syncthreads();

    const int wv  = tid >> 6;          // wave 0..3 -> 16-sample sub-tile
    const int l   = tid & 63;
    const int b   = l >> 2;            // 0..15 (16 lanes share each fbank addr)
    const int sgl = l & 3;             // 4 sample groups x 4 samples = 16
    const int s0  = base + wv * 16 + sgl * 4;

    float w[4];
    #pragma unroll
    for (int j = 0; j < 4; ++j) {
        float p = (s0 + j + 0.5f) * (1.0f / 256.0f) - 0.5f;
        p = fminf(fmaxf(p, 0.f), (float)(NF - 1));
        w[j] = p - (float)i0;
    }

    float a0[4] = {0.f, 0.f, 0.f, 0.f};
    float a1[4] = {0.f, 0.f, 0.f, 0.f};
    const float* gb0 = &g0[b * CPAD];
    const float* gb1 = &g1[b * CPAD];

    #pragma unroll 8
    for (int c = 0; c < NC; ++c) {
        float4 fv = *(const float4*)&fbank[c * NS + s0];
        float q0 = gb0[c];
        float q1 = gb1[c];
        a0[0] = fmaf(q0, fv.x, a0[0]);
        a0[1] = fmaf(q0, fv.y, a0[1]);
        a0[2] = fmaf(q0, fv.z, a0[2]);
        a0[3] = fmaf(q0, fv.w, a0[3]);
        a1[0] = fmaf(q1, fv.x, a1[0]);
        a1[1] = fmaf(q1, fv.y, a1[1]);
        a1[2] = fmaf(q1, fv.z, a1[2]);
        a1[3] = fmaf(q1, fv.w, a1[3]);
    }

    const float inv = 1.0f / (float)NC;
    float4 r;
    r.x = ((1.f - w[0]) * a0[0] + w[0] * a1[0]) * inv;
    r.y = ((1.f - w[1]) * a0[1] + w[1] * a1[1]) * inv;
    r.z = ((1.f - w[2]) * a0[2] + w[2] * a1[2]) * inv;
    r.w = ((1.f - w[3]) * a0[3] + w[3] * a1[3]) * inv;
    *(float4*)&out[b * NS + s0] = r;
}

extern "C" void kernel_launch(void* const* d_in, const int* in_sizes, int n_in,
                              void* d_out, int out_size, void* d_ws, size_t ws_size,
                              hipStream_t stream) {
    const float* x    = (const float*)d_in[0]; // (16,128,64)
    const float* res  = (const float*)d_in[1]; // (64,128)
    const float* fbk  = (const float*)d_in[2]; // (1,128,32768)
    float* out        = (float*)d_out;         // (16,1,32768)
    float* framesT    = (float*)d_ws;          // (128,16,128) = 1 MB

    frames_kernel<<<NB * NC, 64, 0, stream>>>(x, res, framesT);
    mix_kernel<<<NS / TS, 256, 0, stream>>>(framesT, fbk, out);
}

// Round 2
// 83.059 us; speedup vs baseline: 1.0049x; 1.0049x over previous
//
#include <hip/hip_runtime.h>

#define NB 16      // batch
#define NC 128     // bands
#define NR 64      // resolution
#define NF 128     // frames
#define NS 32768   // samples
#define TS 64      // samples per tile in mix kernel
#define BPB 4      // batches per mix block
#define QSTR 33    // LDS chunk stride: (4b+cq)*33+k mod 32 = 4b+cq+k -> 16 distinct banks

// Kernel A: per (b,c) row — softmax over resolution, then matvec with
// resonance (R x F) -> framesT stored TRANSPOSED as (f, b, c).
__global__ __launch_bounds__(64) void frames_kernel(
    const float* __restrict__ x,         // (B, C, R)
    const float* __restrict__ resonance, // (R, F)
    float* __restrict__ framesT)         // (F, B*C)
{
    const int row = blockIdx.x;   // b*128 + c
    const int r   = threadIdx.x;  // 0..63  (one wave)

    float xv = x[row * NR + r];

    float m = xv;
    #pragma unroll
    for (int off = 32; off >= 1; off >>= 1)
        m = fmaxf(m, __shfl_xor(m, off, 64));
    float e = __expf(xv - m);
    float ssum = e;
    #pragma unroll
    for (int off = 32; off >= 1; off >>= 1)
        ssum += __shfl_xor(ssum, off, 64);
    float p = e / ssum;

    __shared__ float psh[NR];
    psh[r] = p;
    __syncthreads();

    float acc0 = 0.f, acc1 = 0.f;
    #pragma unroll 8
    for (int rr = 0; rr < NR; ++rr) {
        float pr = psh[rr];
        acc0 = fmaf(pr, resonance[rr * NF + r],      acc0);
        acc1 = fmaf(pr, resonance[rr * NF + r + 64], acc1);
    }
    framesT[r        * (NB * NC) + row] = acc0;
    framesT[(r + 64) * (NB * NC) + row] = acc1;
}

// Kernel B, restructured for latency hiding:
//   grid = 512 tiles x 4 batch-groups = 2048 blocks (4x occupancy).
//   Each block: 64 samples x 4 batches x all 128 bands.
//   Wave lane decomposition: cq = l>>4 (c-quarter), b = (l>>2)&3, g = l&3.
//   Inner loop is 32 iterations (c-quarter), 4 cache lines in flight per
//   load instr -> ~16x more bytes in flight per CU than the 512-block
//   version. Final sum over cq via 2 shfl_xor steps.
//   XCD decode keeps the 4 blocks sharing one fbank tile on one XCD
//   (bid&7 = XCD round-robin) so fbank HBM traffic stays ~17 MB.
__global__ __launch_bounds__(256, 4) void mix_kernel(
    const float* __restrict__ framesT, // (F, B*C)
    const float* __restrict__ fbank,   // (C, S)
    float* __restrict__ out)           // (B, S)
{
    __shared__ float g0[16 * QSTR];   // 4 batches x 4 c-quarters, stride-33 chunks
    __shared__ float g1[16 * QSTR];

    const int bid  = blockIdx.x;
    const int xcd  = bid & 7;
    const int j    = bid >> 3;            // 0..255 within XCD
    const int tile = xcd * 64 + (j & 63); // 0..511 : 64 tiles per XCD
    const int bg   = j >> 6;              // 0..3   : batch-group
    const int b0   = bg * BPB;
    const int base = tile * TS;

    const int tid = threadIdx.x;

    // tile-uniform frame indices (floor((s+0.5)/256-0.5) constant over tile)
    float posb = (base + 0.5f) * (1.0f / 256.0f) - 0.5f;
    int i0 = (int)floorf(posb);
    i0 = i0 < 0 ? 0 : (i0 > NF - 1 ? NF - 1 : i0);
    const int i1 = (i0 + 1 < NF) ? i0 + 1 : NF - 1;

    // Stage 2 x 512 floats (4 batches x 128 bands) into chunked LDS layout:
    // chunk (b,cq) at offset (4b+cq)*33, element k = c&31 inside.
    // float4: t4 in [0,128) covers one buffer; tid<128 -> g0, else g1.
    {
        const int t4   = tid & 127;
        const int b    = t4 >> 5;          // 0..3
        const int c4   = (t4 & 31) * 4;    // 0,4,...,124
        const int A    = ((b << 2) + (c4 >> 5)) * QSTR + (c4 & 31);
        const int fidx = (tid < 128) ? i0 : i1;
        float* dst     = (tid < 128) ? g0 : g1;
        float4 v = *(const float4*)&framesT[(size_t)fidx * (NB * NC) + b0 * NC + t4 * 4];
        *(float4*)&dst[A] = v;   // A is 4-aligned within a 33-stride chunk (k<=28)
    }
    __syncthreads();

    const int wv = tid >> 6;     // wave 0..3 -> 16-sample sub-tile
    const int l  = tid & 63;
    const int cq = l >> 4;       // c-quarter 0..3
    const int b  = (l >> 2) & 3; // batch within group
    const int g  = l & 3;        // sample group (4 samples)
    const int s0 = base + wv * 16 + g * 4;

    float w[4];
    #pragma unroll
    for (int jj = 0; jj < 4; ++jj) {
        float p = (s0 + jj + 0.5f) * (1.0f / 256.0f) - 0.5f;
        p = fminf(fmaxf(p, 0.f), (float)(NF - 1));
        w[jj] = p - (float)i0;
    }

    const float* q0p = &g0[((b << 2) + cq) * QSTR];
    const float* q1p = &g1[((b << 2) + cq) * QSTR];
    const float* fb  = &fbank[(size_t)(cq * 32) * NS + s0];

    float a0[4] = {0.f, 0.f, 0.f, 0.f};
    float a1[4] = {0.f, 0.f, 0.f, 0.f};

    #pragma unroll 8
    for (int k = 0; k < 32; ++k) {
        float4 fv = *(const float4*)&fb[(size_t)k * NS];
        float q0 = q0p[k];
        float q1 = q1p[k];
        a0[0] = fmaf(q0, fv.x, a0[0]);
        a0[1] = fmaf(q0, fv.y, a0[1]);
        a0[2] = fmaf(q0, fv.z, a0[2]);
        a0[3] = fmaf(q0, fv.w, a0[3]);
        a1[0] = fmaf(q1, fv.x, a1[0]);
        a1[1] = fmaf(q1, fv.y, a1[1]);
        a1[2] = fmaf(q1, fv.z, a1[2]);
        a1[3] = fmaf(q1, fv.w, a1[3]);
    }

    // reduce over cq (lane bits 4,5)
    #pragma unroll
    for (int jj = 0; jj < 4; ++jj) {
        a0[jj] += __shfl_xor(a0[jj], 16, 64);
        a0[jj] += __shfl_xor(a0[jj], 32, 64);
        a1[jj] += __shfl_xor(a1[jj], 16, 64);
        a1[jj] += __shfl_xor(a1[jj], 32, 64);
    }

    if (cq == 0) {
        const float inv = 1.0f / (float)NC;
        float4 r;
        r.x = ((1.f - w[0]) * a0[0] + w[0] * a1[0]) * inv;
        r.y = ((1.f - w[1]) * a0[1] + w[1] * a1[1]) * inv;
        r.z = ((1.f - w[2]) * a0[2] + w[2] * a1[2]) * inv;
        r.w = ((1.f - w[3]) * a0[3] + w[3] * a1[3]) * inv;
        *(float4*)&out[(b0 + b) * NS + s0] = r;
    }
}

extern "C" void kernel_launch(void* const* d_in, const int* in_sizes, int n_in,
                              void* d_out, int out_size, void* d_ws, size_t ws_size,
                              hipStream_t stream) {
    const float* x    = (const float*)d_in[0]; // (16,128,64)
    const float* res  = (const float*)d_in[1]; // (64,128)
    const float* fbk  = (const float*)d_in[2]; // (1,128,32768)
    float* out        = (float*)d_out;         // (16,1,32768)
    float* framesT    = (float*)d_ws;          // (128,16,128) = 1 MB

    frames_kernel<<<NB * NC, 64, 0, stream>>>(x, res, framesT);
    mix_kernel<<<(NS / TS) * (NB / BPB), 256, 0, stream>>>(framesT, fbk, out);
}

// Round 4
// 82.790 us; speedup vs baseline: 1.0082x; 1.0032x over previous
//
#include <hip/hip_runtime.h>

#define NB 16      // batch
#define NC 128     // bands
#define NR 64      // resolution
#define NF 128     // frames
#define NS 32768   // samples
#define TS 64      // samples per tile in mix kernel
#define CPAD 132   // padded LDS row stride (floats) — kills 4-way bank conflict

// Kernel A: softmax over resolution per (b,c) row, then matvec with
// resonance (R x F) -> framesT stored TRANSPOSED as (f, b*c).
// 512 blocks x 256 threads; each wave owns one row (4 rows per block).
__global__ __launch_bounds__(256) void frames_kernel(
    const float* __restrict__ x,         // (B, C, R)
    const float* __restrict__ resonance, // (R, F)
    float* __restrict__ framesT)         // (F, B*C)
{
    const int wv  = threadIdx.x >> 6;           // wave 0..3
    const int r   = threadIdx.x & 63;           // lane = resolution index
    const int row = blockIdx.x * 4 + wv;        // b*128 + c

    float xv = x[row * NR + r];

    // wave-64 reductions: max, then sum of exp
    float m = xv;
    #pragma unroll
    for (int off = 32; off >= 1; off >>= 1)
        m = fmaxf(m, __shfl_xor(m, off, 64));
    float e = __expf(xv - m);
    float ssum = e;
    #pragma unroll
    for (int off = 32; off >= 1; off >>= 1)
        ssum += __shfl_xor(ssum, off, 64);
    float p = e / ssum;

    __shared__ float psh[4][NR];
    psh[wv][r] = p;
    __syncthreads();

    // lane r computes frames f = r and f = r + 64
    float acc0 = 0.f, acc1 = 0.f;
    #pragma unroll 8
    for (int rr = 0; rr < NR; ++rr) {
        float pr = psh[wv][rr];
        acc0 = fmaf(pr, resonance[rr * NF + r],      acc0);
        acc1 = fmaf(pr, resonance[rr * NF + r + 64], acc1);
    }
    framesT[r        * (NB * NC) + row] = acc0;
    framesT[(r + 64) * (NB * NC) + row] = acc1;
}

// Kernel B: one block per 64-sample tile (512 blocks x 256 threads).
// i0/i1 are tile-uniform (floor((s+0.5)/256-0.5) constant over an aligned
// 64-run). Stage frames rows i0,i1 (2 x 8 KB) in LDS with padded stride,
// stream fbank once, 16-way batch replication inside the coalescing
// window (b = lane>>2 -> one 64 B line per wave-load).
__global__ __launch_bounds__(256) void mix_kernel(
    const float* __restrict__ framesT, // (F, B*C)
    const float* __restrict__ fbank,   // (C, S)
    float* __restrict__ out)           // (B, S)
{
    __shared__ float g0[NB * CPAD];
    __shared__ float g1[NB * CPAD];

    const int base = blockIdx.x * TS;
    const int tid  = threadIdx.x;

    float posb = (base + 0.5f) * (1.0f / 256.0f) - 0.5f;
    int i0 = (int)floorf(posb);
    i0 = i0 < 0 ? 0 : (i0 > NF - 1 ? NF - 1 : i0);
    const int i1 = (i0 + 1 < NF) ? i0 + 1 : NF - 1;

    {   // stage 2 x 2048 floats as float4 into padded [b][c] layout
        const float4* src0 = (const float4*)(framesT + (size_t)i0 * (NB * NC));
        const float4* src1 = (const float4*)(framesT + (size_t)i1 * (NB * NC));
        int bb = tid >> 5;
        int cc = (tid & 31) * 4;
        *(float4*)&g0[bb * CPAD + cc] = src0[tid];
        *(float4*)&g1[bb * CPAD + cc] = src1[tid];
        bb = (tid + 256) >> 5;
        cc = ((tid + 256) & 31) * 4;
        *(float4*)&g0[bb * CPAD + cc] = src0[tid + 256];
        *(float4*)&g1[bb * CPAD + cc] = src1[tid + 256];
    }
    __syncthreads();

    const int wv  = tid >> 6;          // wave -> 16-sample sub-tile
    const int l   = tid & 63;
    const int b   = l >> 2;            // 16 lanes share each fbank address
    const int sgl = l & 3;
    const int s0  = base + wv * 16 + sgl * 4;

    float w[4];
    #pragma unroll
    for (int j = 0; j < 4; ++j) {
        float p = (s0 + j + 0.5f) * (1.0f / 256.0f) - 0.5f;
        p = fminf(fmaxf(p, 0.f), (float)(NF - 1));
        w[j] = p - (float)i0;
    }

    float a0[4] = {0.f, 0.f, 0.f, 0.f};
    float a1[4] = {0.f, 0.f, 0.f, 0.f};
    const float* gb0 = &g0[b * CPAD];
    const float* gb1 = &g1[b * CPAD];

    #pragma unroll 8
    for (int c = 0; c < NC; ++c) {
        float4 fv = *(const float4*)&fbank[c * NS + s0];
        float q0 = gb0[c];
        float q1 = gb1[c];
        a0[0] = fmaf(q0, fv.x, a0[0]);
        a0[1] = fmaf(q0, fv.y, a0[1]);
        a0[2] = fmaf(q0, fv.z, a0[2]);
        a0[3] = fmaf(q0, fv.w, a0[3]);
        a1[0] = fmaf(q1, fv.x, a1[0]);
        a1[1] = fmaf(q1, fv.y, a1[1]);
        a1[2] = fmaf(q1, fv.z, a1[2]);
        a1[3] = fmaf(q1, fv.w, a1[3]);
    }

    const float inv = 1.0f / (float)NC;
    float4 r;
    r.x = ((1.f - w[0]) * a0[0] + w[0] * a1[0]) * inv;
    r.y = ((1.f - w[1]) * a0[1] + w[1] * a1[1]) * inv;
    r.z = ((1.f - w[2]) * a0[2] + w[2] * a1[2]) * inv;
    r.w = ((1.f - w[3]) * a0[3] + w[3] * a1[3]) * inv;
    *(float4*)&out[b * NS + s0] = r;
}

extern "C" void kernel_launch(void* const* d_in, const int* in_sizes, int n_in,
                              void* d_out, int out_size, void* d_ws, size_t ws_size,
                              hipStream_t stream) {
    const float* x    = (const float*)d_in[0]; // (16,128,64)
    const float* res  = (const float*)d_in[1]; // (64,128)
    const float* fbk  = (const float*)d_in[2]; // (1,128,32768)
    float* out        = (float*)d_out;         // (16,1,32768)
    float* framesT    = (float*)d_ws;          // (128,16,128) = 1 MB

    frames_kernel<<<(NB * NC) / 4, 256, 0, stream>>>(x, res, framesT);
    mix_kernel<<<NS / TS, 256, 0, stream>>>(framesT, fbk, out);
}